// Round 8
// baseline (85.697 us; speedup 1.0000x reference)
//
#include <hip/hip_runtime.h>
#include <hip/hip_bf16.h>

typedef __bf16 bf16x8 __attribute__((ext_vector_type(8)));
typedef float  f32x4  __attribute__((ext_vector_type(4)));

#define B_SZ 4096
#define I_SZ 512
#define O_SZ 64
#define E_SZ 128
#define BM   256
#define G_EXP 8      // experts per workgroup (K-split group size)
#define EG_N  16     // expert groups
#define MT_N  16     // m tiles (4096/256)

// ---------------- fused prep: x f32->bf16  +  gT[e][b] ----------------
__global__ void prep_xg(const float* __restrict__ x, __bf16* __restrict__ xb,
                        const float* __restrict__ ds, const float* __restrict__ ts,
                        float* __restrict__ gT) {
  int i = blockIdx.x * 256 + threadIdx.x;          // 524288 = B*I/4 = E*B
  float4 v = ((const float4*)x)[i];
  union { __bf16 h[4]; ushort4 u4; } pk;
  pk.h[0] = (__bf16)v.x; pk.h[1] = (__bf16)v.y;
  pk.h[2] = (__bf16)v.z; pk.h[3] = (__bf16)v.w;
  ((ushort4*)xb)[i] = pk.u4;
  int e = i >> 12, b = i & 4095;
  gT[i] = ds[b * 32 + (e >> 2)] * ts[b * 4 + (e & 3)];
}

// ---------------- prep: W [e][i][o] f32 -> wt [e][o][i] bf16 ----------------
__global__ void prep_w(const float* __restrict__ W, __bf16* __restrict__ wt) {
  __shared__ __bf16 tile[64][66];
  int e  = blockIdx.x >> 3;
  int it = blockIdx.x & 7;
  const float* src = W + (size_t)e * I_SZ * O_SZ + (size_t)it * 64 * O_SZ;
  #pragma unroll
  for (int s = 0; s < 16; ++s) {
    int idx = s * 256 + threadIdx.x;
    int r = idx >> 6, o = idx & 63;
    tile[o][r] = (__bf16)src[idx];
  }
  __syncthreads();
  __bf16* dst = wt + (size_t)e * O_SZ * I_SZ + it * 64;
  #pragma unroll
  for (int s = 0; s < 4; ++s) {
    int idx = s * 256 + threadIdx.x;
    int o = idx >> 4, c = (idx & 15) << 2;
    union { __bf16 h[4]; ushort4 u4; } q;
    q.h[0] = tile[o][c + 0]; q.h[1] = tile[o][c + 1];
    q.h[2] = tile[o][c + 2]; q.h[3] = tile[o][c + 3];
    *(ushort4*)&dst[(size_t)o * I_SZ + c] = q.u4;
  }
}

// ---------------- main: fat expert phases, 128B-stride chunked LDS ----------------
// 8 waves x 32 rows (Mf=2 of 16) = BM 256; mfma_f32_16x16x32_bf16, Nf=4 covers O=64.
// Chunked LDS layout [buf][kc][o*64+slot*8] (128B row stride) = measured ZERO bank
// conflicts (R7). Expert loop FULLY UNROLLED (rule #20: runtime-indexed bv[e] went
// to scratch in R7 -> 59MB/117MB scratch traffic; static indexing fixes it).
// Zero VMEM in steady-state loop besides the 8 staging DMAs -> vmcnt exact.
__global__ __launch_bounds__(512, 2)
void mtc_gemm(const __bf16* __restrict__ xb, const __bf16* __restrict__ wt,
              const float* __restrict__ gT, const float* __restrict__ bias,
              float* __restrict__ partials) {
  __shared__ __align__(16) __bf16 wsh[2][8][64 * 64];  // [buf][kc][o*64+slot*8] 8KB chunks
  __shared__ float gsh[G_EXP][BM];                     // 8KB gates

  const int tid  = threadIdx.x;
  const int wave = tid >> 6;
  const int lane = tid & 63;

  // XCD swizzle: 256 blocks -> 32 consecutive per XCD
  int bid = (int)blockIdx.x;
  bid = (bid & 7) * 32 + (bid >> 3);
  const int mtile = bid & 15;
  const int eg    = bid >> 4;
  const int row0  = mtile * BM;
  const int e0    = eg * G_EXP;

  // stage whole expert e into wsh[sbuf]: 8 DMAs/thread, one per 8KB chunk.
  // dest linear (chunk_base + tid*16B) => [o=tid>>3][slot p=tid&7]; source picks
  // logical slot sl = p^(o&7)  (involution; read applies same XOR).
  auto stage = [&](int sbuf, int e) {
    const __bf16* wsrc = wt + (size_t)(e0 + e) * O_SZ * I_SZ;
    int o = tid >> 3, p = tid & 7;
    int sl = p ^ (o & 7);
    #pragma unroll
    for (int kc = 0; kc < 8; ++kc) {
      __builtin_amdgcn_global_load_lds(
          (const __attribute__((address_space(1))) void*)(wsrc + (size_t)o * I_SZ + kc * 64 + sl * 8),
          (__attribute__((address_space(3))) void*)(&wsh[sbuf][kc][wave * 512]),
          16, 0, 0);
    }
  };

  // prologue: stage expert 0, overlap with gsh + af + bias loads
  stage(0, 0);

  for (int idx = tid; idx < G_EXP * BM; idx += 512)
    gsh[idx >> 8][idx & 255] =
        gT[(size_t)(e0 + (idx >> 8)) * B_SZ + row0 + (idx & 255)];

  // x A-fragments: af[mf][j] = x[row0+wave*32+mf*16+(lane&15)][j*32+(lane>>4)*8 ..+8]
  bf16x8 af[2][16];
  {
    const __bf16* xr = xb + (size_t)(row0 + wave * 32 + (lane & 15)) * I_SZ
                          + (lane >> 4) * 8;
    #pragma unroll
    for (int mf = 0; mf < 2; ++mf)
      #pragma unroll
      for (int j = 0; j < 16; ++j)
        af[mf][j] = *(const bf16x8*)(xr + mf * 16 * I_SZ + j * 32);
  }

  // bias hoist: all 8 experts x 4 nf (32 VGPR); static indexing only (loop unrolled)
  float bv[G_EXP][4];
  #pragma unroll
  for (int e = 0; e < G_EXP; ++e)
    #pragma unroll
    for (int nf = 0; nf < 4; ++nf)
      bv[e][nf] = bias[(size_t)(e0 + e) * O_SZ + nf * 16 + (lane & 15)];

  __syncthreads();                     // drains DMA(e0) + af + bias + gsh

  f32x4 logits[2][4] = {};
  #pragma unroll
  for (int e = 0; e < G_EXP; ++e) {    // FULLY UNROLLED: all indices compile-time
    const int buf = e & 1;
    if (e < G_EXP - 1) {
      stage(buf ^ 1, e + 1);                       // 8 DMAs into other buffer
      asm volatile("s_waitcnt vmcnt(8)" ::: "memory");   // stage(e) landed
    } else {
      asm volatile("s_waitcnt vmcnt(0)" ::: "memory");
    }
    __builtin_amdgcn_s_barrier();                  // buf ready for all waves

    f32x4 acc[2][4];
    #pragma unroll
    for (int mf = 0; mf < 2; ++mf)
      #pragma unroll
      for (int nf = 0; nf < 4; ++nf)
        acc[mf][nf] = (f32x4){bv[e][nf], bv[e][nf], bv[e][nf], bv[e][nf]};

    __builtin_amdgcn_s_setprio(1);
    #pragma unroll
    for (int j = 0; j < 16; ++j) {                 // K-steps of 32; chunk = j>>1
      const __bf16* wb = &wsh[buf][j >> 1][0];
      bf16x8 bfr[4];
      #pragma unroll
      for (int nf = 0; nf < 4; ++nf) {
        int o  = nf * 16 + (lane & 15);
        int q  = (j & 1) * 4 + (lane >> 4);
        int ph = q ^ (o & 7);
        bfr[nf] = *(const bf16x8*)(wb + o * 64 + ph * 8);
      }
      #pragma unroll
      for (int nf = 0; nf < 4; ++nf)
        #pragma unroll
        for (int mf = 0; mf < 2; ++mf)
          acc[mf][nf] = __builtin_amdgcn_mfma_f32_16x16x32_bf16(
              af[mf][j], bfr[nf], acc[mf][nf], 0, 0, 0);
    }
    __builtin_amdgcn_s_setprio(0);

    // drain: logits += g[row,e] * (xW+b).  C/D: col=lane&15, row=(lane>>4)*4+rg
    f32x4 gq[2];
    #pragma unroll
    for (int mf = 0; mf < 2; ++mf)
      gq[mf] = *(const f32x4*)&gsh[e][wave * 32 + mf * 16 + (lane >> 4) * 4];
    #pragma unroll
    for (int mf = 0; mf < 2; ++mf)
      #pragma unroll
      for (int nf = 0; nf < 4; ++nf)
        #pragma unroll
        for (int rg = 0; rg < 4; ++rg)
          logits[mf][nf][rg] += gq[mf][rg] * acc[mf][nf][rg];

    __builtin_amdgcn_s_barrier();                  // all waves done reading buf
  }

  float* pout = partials + (size_t)eg * B_SZ * O_SZ + (size_t)row0 * O_SZ;
  #pragma unroll
  for (int mf = 0; mf < 2; ++mf)
    #pragma unroll
    for (int nf = 0; nf < 4; ++nf)
      #pragma unroll
      for (int rg = 0; rg < 4; ++rg) {
        int r = wave * 32 + mf * 16 + ((lane >> 4) << 2) + rg;
        int o = nf * 16 + (lane & 15);
        pout[(size_t)r * O_SZ + o] = logits[mf][nf][rg];
      }
}

// ---------------- reduce: sum partials + log_softmax (bias already in gemm) ----
__global__ __launch_bounds__(256)
void mtc_reduce(const float* __restrict__ partials, float* __restrict__ out) {
  int wave = threadIdx.x >> 6, lane = threadIdx.x & 63;
  int r = blockIdx.x * 4 + wave;                    // one 64-lane wave per row
  float s = 0.f;
  #pragma unroll
  for (int k = 0; k < EG_N; ++k)
    s += partials[(size_t)k * B_SZ * O_SZ + (size_t)r * O_SZ + lane];
  float m = s;
  #pragma unroll
  for (int off = 32; off; off >>= 1) m = fmaxf(m, __shfl_xor(m, off));
  float ex = expf(s - m), sum = ex;
  #pragma unroll
  for (int off = 32; off; off >>= 1) sum += __shfl_xor(sum, off);
  out[(size_t)r * O_SZ + lane] = s - m - logf(sum);
}

extern "C" void kernel_launch(void* const* d_in, const int* in_sizes, int n_in,
                              void* d_out, int out_size, void* d_ws, size_t ws_size,
                              hipStream_t stream) {
  const float* x    = (const float*)d_in[0];
  const float* ds   = (const float*)d_in[1];
  const float* ts   = (const float*)d_in[2];
  const float* W    = (const float*)d_in[3];
  const float* bias = (const float*)d_in[4];
  float* out = (float*)d_out;

  char* w = (char*)d_ws;
  __bf16* xb      = (__bf16*)(w);                   // 4 MB
  __bf16* wt      = (__bf16*)(w + (4ull  << 20));   // 8 MB
  float*  gT      = (float*) (w + (12ull << 20));   // 2 MB
  float*  parts   = (float*) (w + (14ull << 20));   // 16 MB

  prep_xg   <<<2048, 256, 0, stream>>>(x, xb, ds, ts, gT);
  prep_w    <<<1024, 256, 0, stream>>>(W, wt);
  mtc_gemm  <<< 256, 512, 0, stream>>>(xb, wt, gT, bias, parts);
  mtc_reduce<<<1024, 256, 0, stream>>>(parts, out);
}

// Round 9
// 58.185 us; speedup vs baseline: 1.4728x; 1.4728x over previous
//
#include <hip/hip_runtime.h>
#include <hip/hip_bf16.h>

typedef __bf16 bf16x8 __attribute__((ext_vector_type(8)));
typedef float  f32x4  __attribute__((ext_vector_type(4)));

#define B_SZ 4096
#define I_SZ 512
#define O_SZ 64
#define E_SZ 128
#define BM   256
#define G_EXP 8      // experts per workgroup (K-split group size)
#define EG_N  16     // expert groups
#define MT_N  16     // m tiles (4096/256)

// ---------------- fused prep: x f32->bf16  +  gT[e][b] ----------------
__global__ void prep_xg(const float* __restrict__ x, __bf16* __restrict__ xb,
                        const float* __restrict__ ds, const float* __restrict__ ts,
                        float* __restrict__ gT) {
  int i = blockIdx.x * 256 + threadIdx.x;          // 524288 = B*I/4 = E*B
  float4 v = ((const float4*)x)[i];
  union { __bf16 h[4]; ushort4 u4; } pk;
  pk.h[0] = (__bf16)v.x; pk.h[1] = (__bf16)v.y;
  pk.h[2] = (__bf16)v.z; pk.h[3] = (__bf16)v.w;
  ((ushort4*)xb)[i] = pk.u4;
  int e = i >> 12, b = i & 4095;
  gT[i] = ds[b * 32 + (e >> 2)] * ts[b * 4 + (e & 3)];
}

// ---------------- prep: W [e][i][o] f32 -> wt [e][o][i] bf16 ----------------
__global__ void prep_w(const float* __restrict__ W, __bf16* __restrict__ wt) {
  __shared__ __bf16 tile[64][66];
  int e  = blockIdx.x >> 3;
  int it = blockIdx.x & 7;
  const float* src = W + (size_t)e * I_SZ * O_SZ + (size_t)it * 64 * O_SZ;
  #pragma unroll
  for (int s = 0; s < 16; ++s) {
    int idx = s * 256 + threadIdx.x;
    int r = idx >> 6, o = idx & 63;
    tile[o][r] = (__bf16)src[idx];
  }
  __syncthreads();
  __bf16* dst = wt + (size_t)e * O_SZ * I_SZ + it * 64;
  #pragma unroll
  for (int s = 0; s < 4; ++s) {
    int idx = s * 256 + threadIdx.x;
    int o = idx >> 4, c = (idx & 15) << 2;
    union { __bf16 h[4]; ushort4 u4; } q;
    q.h[0] = tile[o][c + 0]; q.h[1] = tile[o][c + 1];
    q.h[2] = tile[o][c + 2]; q.h[3] = tile[o][c + 3];
    *(ushort4*)&dst[(size_t)o * I_SZ + c] = q.u4;
  }
}

// ---------------- main: fat expert phases, 128B-stride chunked LDS ----------------
// 8 waves x 32 rows (Mf=2 of 16) = BM 256; mfma_f32_16x16x32_bf16, Nf=4 covers O=64.
// R5's proven loop structure (runtime e loop, 2 barriers + counted vmcnt(8)/expert,
// 45.8us, no spill) + R7's chunked [buf][kc][o*64+slot*8] LDS (measured ZERO bank
// conflicts). Bias in LDS (2KB), read per expert via ds_read (4 regs live, lgkmcnt)
// -- the R7/R8 bv[8][4] hoist blew the 256-reg combined budget (512-thread block =
// >=2 waves/SIMD -> 256 regs/wave cap) and caused 60/120MB scratch spill traffic.
__global__ __launch_bounds__(512, 2)
void mtc_gemm(const __bf16* __restrict__ xb, const __bf16* __restrict__ wt,
              const float* __restrict__ gT, const float* __restrict__ bias,
              float* __restrict__ partials) {
  __shared__ __align__(16) __bf16 wsh[2][8][64 * 64];  // [buf][kc][o*64+slot*8] 8KB chunks
  __shared__ float gsh[G_EXP][BM];                     // 8KB gates
  __shared__ float bsh[G_EXP][O_SZ];                   // 2KB bias

  const int tid  = threadIdx.x;
  const int wave = tid >> 6;
  const int lane = tid & 63;

  // XCD swizzle: 256 blocks -> 32 consecutive per XCD
  int bid = (int)blockIdx.x;
  bid = (bid & 7) * 32 + (bid >> 3);
  const int mtile = bid & 15;
  const int eg    = bid >> 4;
  const int row0  = mtile * BM;
  const int e0    = eg * G_EXP;

  // stage whole expert e into wsh[sbuf]: 8 DMAs/thread, one per 8KB chunk.
  // dest linear (chunk_base + tid*16B) => [o=tid>>3][slot p=tid&7]; source picks
  // logical slot sl = p^(o&7)  (involution; read applies same XOR).
  auto stage = [&](int sbuf, int e) {
    const __bf16* wsrc = wt + (size_t)(e0 + e) * O_SZ * I_SZ;
    int o = tid >> 3, p = tid & 7;
    int sl = p ^ (o & 7);
    #pragma unroll
    for (int kc = 0; kc < 8; ++kc) {
      __builtin_amdgcn_global_load_lds(
          (const __attribute__((address_space(1))) void*)(wsrc + (size_t)o * I_SZ + kc * 64 + sl * 8),
          (__attribute__((address_space(3))) void*)(&wsh[sbuf][kc][wave * 512]),
          16, 0, 0);
    }
  };

  // prologue: stage expert 0, overlap with gsh + bias + af loads
  stage(0, 0);

  for (int idx = tid; idx < G_EXP * BM; idx += 512)
    gsh[idx >> 8][idx & 255] =
        gT[(size_t)(e0 + (idx >> 8)) * B_SZ + row0 + (idx & 255)];

  bsh[tid >> 6][tid & 63] = bias[(size_t)e0 * O_SZ + tid];   // 512 = G_EXP*O_SZ

  // x A-fragments: af[mf][j] = x[row0+wave*32+mf*16+(lane&15)][j*32+(lane>>4)*8 ..+8]
  bf16x8 af[2][16];
  {
    const __bf16* xr = xb + (size_t)(row0 + wave * 32 + (lane & 15)) * I_SZ
                          + (lane >> 4) * 8;
    #pragma unroll
    for (int mf = 0; mf < 2; ++mf)
      #pragma unroll
      for (int j = 0; j < 16; ++j)
        af[mf][j] = *(const bf16x8*)(xr + mf * 16 * I_SZ + j * 32);
  }

  __syncthreads();                     // drains DMA(e0) + af + bias + gsh

  f32x4 logits[2][4] = {};
  int buf = 0;
  for (int e = 0; e < G_EXP; ++e) {
    if (e < G_EXP - 1) {
      stage(buf ^ 1, e + 1);                       // 8 DMAs into other buffer
      asm volatile("s_waitcnt vmcnt(8)" ::: "memory");   // stage(e) landed
    } else {
      asm volatile("s_waitcnt vmcnt(0)" ::: "memory");
    }
    __builtin_amdgcn_s_barrier();                  // buf ready for all waves

    // bias from LDS: 4 regs live, lgkmcnt (doesn't disturb vmcnt counting)
    float bv[4];
    #pragma unroll
    for (int nf = 0; nf < 4; ++nf)
      bv[nf] = bsh[e][nf * 16 + (lane & 15)];
    f32x4 acc[2][4];
    #pragma unroll
    for (int mf = 0; mf < 2; ++mf)
      #pragma unroll
      for (int nf = 0; nf < 4; ++nf)
        acc[mf][nf] = (f32x4){bv[nf], bv[nf], bv[nf], bv[nf]};

    __builtin_amdgcn_s_setprio(1);
    #pragma unroll
    for (int j = 0; j < 16; ++j) {                 // K-steps of 32; chunk = j>>1
      const __bf16* wb = &wsh[buf][j >> 1][0];
      bf16x8 bfr[4];
      #pragma unroll
      for (int nf = 0; nf < 4; ++nf) {
        int o  = nf * 16 + (lane & 15);
        int q  = (j & 1) * 4 + (lane >> 4);
        int ph = q ^ (o & 7);
        bfr[nf] = *(const bf16x8*)(wb + o * 64 + ph * 8);
      }
      #pragma unroll
      for (int nf = 0; nf < 4; ++nf)
        #pragma unroll
        for (int mf = 0; mf < 2; ++mf)
          acc[mf][nf] = __builtin_amdgcn_mfma_f32_16x16x32_bf16(
              af[mf][j], bfr[nf], acc[mf][nf], 0, 0, 0);
    }
    __builtin_amdgcn_s_setprio(0);

    // drain: logits += g[row,e] * (xW+b).  C/D: col=lane&15, row=(lane>>4)*4+rg
    f32x4 gq[2];
    #pragma unroll
    for (int mf = 0; mf < 2; ++mf)
      gq[mf] = *(const f32x4*)&gsh[e][wave * 32 + mf * 16 + (lane >> 4) * 4];
    #pragma unroll
    for (int mf = 0; mf < 2; ++mf)
      #pragma unroll
      for (int nf = 0; nf < 4; ++nf)
        #pragma unroll
        for (int rg = 0; rg < 4; ++rg)
          logits[mf][nf][rg] += gq[mf][rg] * acc[mf][nf][rg];

    __builtin_amdgcn_s_barrier();                  // all waves done reading buf
    buf ^= 1;
  }

  float* pout = partials + (size_t)eg * B_SZ * O_SZ + (size_t)row0 * O_SZ;
  #pragma unroll
  for (int mf = 0; mf < 2; ++mf)
    #pragma unroll
    for (int nf = 0; nf < 4; ++nf)
      #pragma unroll
      for (int rg = 0; rg < 4; ++rg) {
        int r = wave * 32 + mf * 16 + ((lane >> 4) << 2) + rg;
        int o = nf * 16 + (lane & 15);
        pout[(size_t)r * O_SZ + o] = logits[mf][nf][rg];
      }
}

// ---------------- reduce: sum partials + log_softmax (bias already in gemm) ----
__global__ __launch_bounds__(256)
void mtc_reduce(const float* __restrict__ partials, float* __restrict__ out) {
  int wave = threadIdx.x >> 6, lane = threadIdx.x & 63;
  int r = blockIdx.x * 4 + wave;                    // one 64-lane wave per row
  float s = 0.f;
  #pragma unroll
  for (int k = 0; k < EG_N; ++k)
    s += partials[(size_t)k * B_SZ * O_SZ + (size_t)r * O_SZ + lane];
  float m = s;
  #pragma unroll
  for (int off = 32; off; off >>= 1) m = fmaxf(m, __shfl_xor(m, off));
  float ex = expf(s - m), sum = ex;
  #pragma unroll
  for (int off = 32; off; off >>= 1) sum += __shfl_xor(sum, off);
  out[(size_t)r * O_SZ + lane] = s - m - logf(sum);
}

extern "C" void kernel_launch(void* const* d_in, const int* in_sizes, int n_in,
                              void* d_out, int out_size, void* d_ws, size_t ws_size,
                              hipStream_t stream) {
  const float* x    = (const float*)d_in[0];
  const float* ds   = (const float*)d_in[1];
  const float* ts   = (const float*)d_in[2];
  const float* W    = (const float*)d_in[3];
  const float* bias = (const float*)d_in[4];
  float* out = (float*)d_out;

  char* w = (char*)d_ws;
  __bf16* xb      = (__bf16*)(w);                   // 4 MB
  __bf16* wt      = (__bf16*)(w + (4ull  << 20));   // 8 MB
  float*  gT      = (float*) (w + (12ull << 20));   // 2 MB
  float*  parts   = (float*) (w + (14ull << 20));   // 16 MB

  prep_xg   <<<2048, 256, 0, stream>>>(x, xb, ds, ts, gT);
  prep_w    <<<1024, 256, 0, stream>>>(W, wt);
  mtc_gemm  <<< 256, 512, 0, stream>>>(xb, wt, gT, bias, parts);
  mtc_reduce<<<1024, 256, 0, stream>>>(parts, out);
}